// Round 4
// baseline (970.230 us; speedup 1.0000x reference)
//
#include <hip/hip_runtime.h>

#define N_NODES   50000
#define N_EDGES   800000
#define DF        64          // feature dim (D_IN == D_HID == 64)
#define N_GRAPHS  64
#define NPAD      50176       // 196*256, padded node count for the scan

// ---------------- CSR build: count -> scan -> fill ----------------

__global__ void k_count(const int* __restrict__ col, int* __restrict__ cnt) {
    int e = blockIdx.x * blockDim.x + threadIdx.x;
    if (e < N_EDGES) atomicAdd(&cnt[col[e]], 1);
}

__global__ void k_dinv(const int* __restrict__ cnt, float* __restrict__ dinv) {
    int i = blockIdx.x * blockDim.x + threadIdx.x;
    if (i < N_NODES) dinv[i] = rsqrtf((float)(cnt[i] + 1));   // +1 self-loop
}

// per-block exclusive scan (Hillis-Steele), 196 blocks x 256
__global__ __launch_bounds__(256)
void k_scan_block(const int* __restrict__ cnt, int* __restrict__ offs,
                  int* __restrict__ bsum) {
    __shared__ int s[256];
    int t = threadIdx.x;
    int i = blockIdx.x * 256 + t;
    int v = cnt[i];
    s[t] = v; __syncthreads();
    #pragma unroll
    for (int off = 1; off < 256; off <<= 1) {
        int x = (t >= off) ? s[t - off] : 0;
        __syncthreads();
        s[t] += x;
        __syncthreads();
    }
    offs[i] = s[t] - v;                    // exclusive
    if (t == 255) bsum[blockIdx.x] = s[255];
}

__global__ void k_scan_bsum(int* __restrict__ bsum) {
    if (threadIdx.x == 0 && blockIdx.x == 0) {
        int run = 0;
        for (int b = 0; b < 196; ++b) { int v = bsum[b]; bsum[b] = run; run += v; }
    }
}

__global__ void k_scan_add(int* __restrict__ offs, const int* __restrict__ bsum,
                           int* __restrict__ cursor) {
    int i = blockIdx.x * 256 + threadIdx.x;
    int v = offs[i] + bsum[blockIdx.x];
    offs[i] = v; cursor[i] = v;
}

__global__ void k_fill(const int* __restrict__ row, const int* __restrict__ col,
                       int* __restrict__ cursor, int* __restrict__ esrc) {
    int e = blockIdx.x * blockDim.x + threadIdx.x;
    if (e < N_EDGES) {
        int slot = atomicAdd(&cursor[col[e]], 1);
        esrc[slot] = row[e];
    }
}

// ---------------- fused layer: h_out = relu( (A_hat X) W + b ) ----------------
// Uses A_hat (X W) == (A_hat X) W.  64 destination nodes per block, 256 threads.
// Phase 1 (gather): wave w handles 16 nodes sequentially; lane = feature d.
//   agg[n] = dinv[n] * ( dinv[n]*X[n] + sum_{r in in(n)} dinv[r]*X[r] )
//   stored transposed into LDS: XsT[d][n_local]  (LDX=68 keeps b128 reads clean)
// Phase 2 (gemm): round-3 register-tiled 64x64 @ 64x64, bias+relu epilogue.
#define GB 64
#define LDX 68

__global__ __launch_bounds__(256)
void k_layer(const int* __restrict__ offs, const int* __restrict__ esrc,
             const float* __restrict__ dinv, const float* __restrict__ X,
             const float* __restrict__ W, const float* __restrict__ bias,
             float* __restrict__ out) {
    __shared__ float XsT[DF][LDX];   // 17.4 KB
    __shared__ float Ws[DF][DF];     // 16 KB

    const int t = threadIdx.x;
    const int row0 = blockIdx.x * GB;

    // stage W (4096 floats, float4 coalesced)
    for (int idx = t * 4; idx < DF * DF; idx += 256 * 4) {
        float4 w = *(const float4*)&W[idx];
        Ws[idx >> 6][(idx & 63) + 0] = w.x;
        Ws[idx >> 6][(idx & 63) + 1] = w.y;
        Ws[idx >> 6][(idx & 63) + 2] = w.z;
        Ws[idx >> 6][(idx & 63) + 3] = w.w;
    }

    // phase 1: gather aggregation of raw X
    const int wv = t >> 6;
    const int d  = t & 63;
    for (int u = 0; u < 16; ++u) {
        const int nl = wv * 16 + u;
        const int n  = row0 + nl;
        float res = 0.f;
        if (n < N_NODES) {
            float dc  = dinv[n];
            float acc = X[n * DF + d] * dc;            // self-loop
            int s  = offs[n];
            int s1 = offs[n + 1];
            for (; s + 8 <= s1; s += 8) {              // x8 unroll for MLP
                int r0 = esrc[s + 0], r1 = esrc[s + 1];
                int r2 = esrc[s + 2], r3 = esrc[s + 3];
                int r4 = esrc[s + 4], r5 = esrc[s + 5];
                int r6 = esrc[s + 6], r7 = esrc[s + 7];
                float w0 = dinv[r0], w1 = dinv[r1], w2 = dinv[r2], w3 = dinv[r3];
                float w4 = dinv[r4], w5 = dinv[r5], w6 = dinv[r6], w7 = dinv[r7];
                float v0 = X[r0 * DF + d], v1 = X[r1 * DF + d];
                float v2 = X[r2 * DF + d], v3 = X[r3 * DF + d];
                float v4 = X[r4 * DF + d], v5 = X[r5 * DF + d];
                float v6 = X[r6 * DF + d], v7 = X[r7 * DF + d];
                acc += v0 * w0; acc += v1 * w1; acc += v2 * w2; acc += v3 * w3;
                acc += v4 * w4; acc += v5 * w5; acc += v6 * w6; acc += v7 * w7;
            }
            for (; s < s1; ++s) {
                int r = esrc[s];
                acc += X[r * DF + d] * dinv[r];
            }
            res = acc * dc;
        }
        XsT[d][nl] = res;
    }
    __syncthreads();

    // phase 2: out_tile = relu( agg_tile @ W + b )
    const int i = (t & 15) * 4;   // row offset in tile
    const int j = (t >> 4) * 4;   // col offset
    float acc[4][4] = {};
    #pragma unroll
    for (int k = 0; k < DF; ++k) {
        float4 xv = *(const float4*)&XsT[k][i];
        float4 wvv = *(const float4*)&Ws[k][j];
        acc[0][0] += xv.x * wvv.x; acc[0][1] += xv.x * wvv.y;
        acc[0][2] += xv.x * wvv.z; acc[0][3] += xv.x * wvv.w;
        acc[1][0] += xv.y * wvv.x; acc[1][1] += xv.y * wvv.y;
        acc[1][2] += xv.y * wvv.z; acc[1][3] += xv.y * wvv.w;
        acc[2][0] += xv.z * wvv.x; acc[2][1] += xv.z * wvv.y;
        acc[2][2] += xv.z * wvv.z; acc[2][3] += xv.z * wvv.w;
        acc[3][0] += xv.w * wvv.x; acc[3][1] += xv.w * wvv.y;
        acc[3][2] += xv.w * wvv.z; acc[3][3] += xv.w * wvv.w;
    }
    float4 bb = *(const float4*)&bias[j];
    #pragma unroll
    for (int u = 0; u < 4; ++u) {
        int gr = row0 + i + u;
        if (gr < N_NODES) {
            float4 o;
            o.x = acc[u][0] + bb.x; o.x = o.x > 0.f ? o.x : 0.f;
            o.y = acc[u][1] + bb.y; o.y = o.y > 0.f ? o.y : 0.f;
            o.z = acc[u][2] + bb.z; o.z = o.z > 0.f ? o.z : 0.f;
            o.w = acc[u][3] + bb.w; o.w = o.w > 0.f ? o.w : 0.f;
            *(float4*)&out[gr * DF + j] = o;
        }
    }
}

// ---------------- hierarchical pool (batch is sorted); input already relu'd ----------------
#define POOL_NPW 128   // nodes per wave

__global__ __launch_bounds__(256)
void k_pool2(const float* __restrict__ h, const int* __restrict__ batch,
             float* __restrict__ pool, float* __restrict__ cnt) {
    const int wave = threadIdx.x >> 6;
    const int d    = threadIdx.x & 63;
    int n0 = (blockIdx.x * 4 + wave) * POOL_NPW;
    if (n0 >= N_NODES) return;
    int n1 = n0 + POOL_NPW; if (n1 > N_NODES) n1 = N_NODES;
    float acc = 0.f, c = 0.f;
    int g = batch[n0];
    for (int n = n0; n < n1; ++n) {
        int bg = batch[n];                 // wave-uniform broadcast
        if (bg != g) {
            atomicAdd(&pool[g * DF + d], acc);
            if (d == 0) atomicAdd(&cnt[g], c);
            acc = 0.f; c = 0.f; g = bg;
        }
        acc += h[n * DF + d];
        c += 1.f;
    }
    atomicAdd(&pool[g * DF + d], acc);
    if (d == 0) atomicAdd(&cnt[g], c);
}

__global__ void k_div(const float* __restrict__ pool, const float* __restrict__ cnt,
                      float* __restrict__ out) {
    int idx = blockIdx.x * blockDim.x + threadIdx.x;
    if (idx < N_GRAPHS * DF) {
        float c = cnt[idx >> 6];
        out[idx] = pool[idx] / fmaxf(c, 1.0f);
    }
}

// ---------------- launch ----------------

extern "C" void kernel_launch(void* const* d_in, const int* in_sizes, int n_in,
                              void* d_out, int out_size, void* d_ws, size_t ws_size,
                              hipStream_t stream) {
    const float* x     = (const float*)d_in[0];
    const int*   ei    = (const int*)d_in[1];      // [2, E] flat: row then col
    const int*   batch = (const int*)d_in[2];
    const float* W1    = (const float*)d_in[3];
    const float* b1    = (const float*)d_in[4];
    const float* W2    = (const float*)d_in[5];
    const float* b2    = (const float*)d_in[6];
    const float* W3    = (const float*)d_in[7];
    const float* b3    = (const float*)d_in[8];
    float* out = (float*)d_out;

    const int* row = ei;             // source
    const int* col = ei + N_EDGES;   // target (aggregation index)

    // workspace layout (4-byte elements)
    char* wsb = (char*)d_ws;
    int*   cnti   = (int*)wsb;                       // NPAD
    int*   offs   = cnti + NPAD;                     // NPAD
    int*   cursor = offs + NPAD;                     // NPAD
    int*   bsum   = cursor + NPAD;                   // 256
    int*   esrc   = bsum + 256;                      // N_EDGES
    float* dinv   = (float*)(esrc + N_EDGES);        // NPAD
    float* bufA   = dinv + NPAD;                     // N_NODES*DF
    float* bufB   = bufA + N_NODES * DF;             // N_NODES*DF
    float* pool   = bufB + N_NODES * DF;             // N_GRAPHS*DF
    float* cnt    = pool + N_GRAPHS * DF;            // N_GRAPHS

    const int nblk_E = (N_EDGES + 255) / 256;        // 3125
    const int nblk_N = (N_NODES + 255) / 256;        // 196
    const int nblk_L = (N_NODES + GB - 1) / GB;      // 782
    const int nblk_P = (N_NODES + 4 * POOL_NPW - 1) / (4 * POOL_NPW); // 98

    // CSR build + dinv
    hipMemsetAsync(cnti, 0, NPAD * sizeof(int), stream);
    k_count<<<nblk_E, 256, 0, stream>>>(col, cnti);
    k_dinv<<<nblk_N, 256, 0, stream>>>(cnti, dinv);
    k_scan_block<<<196, 256, 0, stream>>>(cnti, offs, bsum);
    k_scan_bsum<<<1, 64, 0, stream>>>(bsum);
    k_scan_add<<<196, 256, 0, stream>>>(offs, bsum, cursor);
    k_fill<<<nblk_E, 256, 0, stream>>>(row, col, cursor, esrc);

    // 3 fused GCN layers: h = relu((A_hat X) W + b)
    k_layer<<<nblk_L, 256, 0, stream>>>(offs, esrc, dinv, x,    W1, b1, bufA);
    k_layer<<<nblk_L, 256, 0, stream>>>(offs, esrc, dinv, bufA, W2, b2, bufB);
    k_layer<<<nblk_L, 256, 0, stream>>>(offs, esrc, dinv, bufB, W3, b3, bufA);

    // mean pool
    hipMemsetAsync(pool, 0, (N_GRAPHS * DF + N_GRAPHS) * sizeof(float), stream);
    k_pool2<<<nblk_P, 256, 0, stream>>>(bufA, batch, pool, cnt);
    k_div<<<(N_GRAPHS * DF + 255) / 256, 256, 0, stream>>>(pool, cnt, out);
}

// Round 5
// 405.329 us; speedup vs baseline: 2.3937x; 2.3937x over previous
//
#include <hip/hip_runtime.h>

#define N_NODES   50000
#define N_EDGES   800000
#define DF        64          // feature dim (D_IN == D_HID == 64)
#define N_GRAPHS  64
#define NPAD      50176       // 196*256, padded node count for the scan

// ---------------- CSR build: count -> scan(+dinv) -> fill ----------------

__global__ void k_count(const int* __restrict__ col, int* __restrict__ cnt) {
    int e = blockIdx.x * blockDim.x + threadIdx.x;
    if (e < N_EDGES) atomicAdd(&cnt[col[e]], 1);
}

// per-block exclusive scan (Hillis-Steele), 196 blocks x 256; also emits dinv
__global__ __launch_bounds__(256)
void k_scan_block(const int* __restrict__ cnt, int* __restrict__ offs,
                  int* __restrict__ bsum, float* __restrict__ dinv) {
    __shared__ int s[256];
    int t = threadIdx.x;
    int i = blockIdx.x * 256 + t;
    int v = cnt[i];
    if (i < N_NODES) dinv[i] = rsqrtf((float)(v + 1));   // +1 self-loop
    s[t] = v; __syncthreads();
    #pragma unroll
    for (int off = 1; off < 256; off <<= 1) {
        int x = (t >= off) ? s[t - off] : 0;
        __syncthreads();
        s[t] += x;
        __syncthreads();
    }
    offs[i] = s[t] - v;                    // exclusive
    if (t == 255) bsum[blockIdx.x] = s[255];
}

__global__ void k_scan_bsum(int* __restrict__ bsum) {
    if (threadIdx.x == 0 && blockIdx.x == 0) {
        int run = 0;
        for (int b = 0; b < 196; ++b) { int v = bsum[b]; bsum[b] = run; run += v; }
    }
}

__global__ void k_scan_add(int* __restrict__ offs, const int* __restrict__ bsum,
                           int* __restrict__ cursor) {
    int i = blockIdx.x * 256 + threadIdx.x;
    int v = offs[i] + bsum[blockIdx.x];
    offs[i] = v; cursor[i] = v;
}

__global__ void k_fill(const int* __restrict__ row, const int* __restrict__ col,
                       int* __restrict__ cursor, int* __restrict__ esrc) {
    int e = blockIdx.x * blockDim.x + threadIdx.x;
    if (e < N_EDGES) {
        int slot = atomicAdd(&cursor[col[e]], 1);
        esrc[slot] = row[e];
    }
}

// ---------------- GEMM: out = act(in [+ bias]) @ W ----------------
// 64x64 block tile, 256 threads, 4x4 register tile per thread. (round-3 proven)
#define GB_ROWS 64
#define LDX 68

__global__ __launch_bounds__(256)
void k_gemm(const float* __restrict__ in, const float* __restrict__ W,
            const float* __restrict__ bias, float* __restrict__ out,
            int relu_out) {
    __shared__ float XsT[DF][LDX];   // 17 KB
    __shared__ float Ws[DF][DF];     // 16 KB

    const int t = threadIdx.x;
    const int row0 = blockIdx.x * GB_ROWS;

    for (int idx = t * 4; idx < DF * DF; idx += 256 * 4) {
        float4 w = *(const float4*)&W[idx];
        Ws[idx >> 6][(idx & 63) + 0] = w.x;
        Ws[idx >> 6][(idx & 63) + 1] = w.y;
        Ws[idx >> 6][(idx & 63) + 2] = w.z;
        Ws[idx >> 6][(idx & 63) + 3] = w.w;
    }

    {   // stage X transposed
        const int r  = t >> 2;
        const int k0 = (t & 3) * 16;
        const int gr = row0 + r;
        const bool valid = gr < N_NODES;
        #pragma unroll
        for (int kk = 0; kk < 16; kk += 4) {
            float4 v = valid ? *(const float4*)&in[gr * DF + k0 + kk]
                             : make_float4(0.f, 0.f, 0.f, 0.f);
            XsT[k0 + kk + 0][r] = v.x;
            XsT[k0 + kk + 1][r] = v.y;
            XsT[k0 + kk + 2][r] = v.z;
            XsT[k0 + kk + 3][r] = v.w;
        }
    }
    __syncthreads();

    const int i = (t & 15) * 4;   // row offset in tile
    const int j = (t >> 4) * 4;   // col offset
    float acc[4][4] = {};
    #pragma unroll
    for (int k = 0; k < DF; ++k) {
        float4 xv = *(const float4*)&XsT[k][i];
        float4 wv = *(const float4*)&Ws[k][j];
        acc[0][0] += xv.x * wv.x; acc[0][1] += xv.x * wv.y;
        acc[0][2] += xv.x * wv.z; acc[0][3] += xv.x * wv.w;
        acc[1][0] += xv.y * wv.x; acc[1][1] += xv.y * wv.y;
        acc[1][2] += xv.y * wv.z; acc[1][3] += xv.y * wv.w;
        acc[2][0] += xv.z * wv.x; acc[2][1] += xv.z * wv.y;
        acc[2][2] += xv.z * wv.z; acc[2][3] += xv.z * wv.w;
        acc[3][0] += xv.w * wv.x; acc[3][1] += xv.w * wv.y;
        acc[3][2] += xv.w * wv.z; acc[3][3] += xv.w * wv.w;
    }
    float4 bb = *(const float4*)&bias[j];
    #pragma unroll
    for (int u = 0; u < 4; ++u) {
        int gr = row0 + i + u;
        if (gr < N_NODES) {
            float4 o;
            o.x = acc[u][0] + bb.x;
            o.y = acc[u][1] + bb.y;
            o.z = acc[u][2] + bb.z;
            o.w = acc[u][3] + bb.w;
            if (relu_out) {
                o.x = o.x > 0.f ? o.x : 0.f;
                o.y = o.y > 0.f ? o.y : 0.f;
                o.z = o.z > 0.f ? o.z : 0.f;
                o.w = o.w > 0.f ? o.w : 0.f;
            }
            *(float4*)&out[gr * DF + j] = o;
        }
    }
}

// ---------------- gather aggregation: 4 edges in parallel via lane groups ----------------
// agg[c] = dinv[c] * ( dinv[c]*h[c] + sum_{r in in(c)} dinv[r]*h[r] )
// lane l: g = l>>4 selects edge within quad, q = l&15 selects feature quad.
// Each lane loads float4 of a DIFFERENT source row per iteration -> 4 edges/instr.
// 2x unroll -> 8 edges in flight. Butterfly xor-16/32 folds groups; lanes 0..15 store.
__global__ __launch_bounds__(256)
void k_gather(const int* __restrict__ offs, const int* __restrict__ esrc,
              const float* __restrict__ dinv, const float* __restrict__ h,
              float* __restrict__ agg) {
    const int n = blockIdx.x * 4 + (threadIdx.x >> 6);
    if (n >= N_NODES) return;
    const int l = threadIdx.x & 63;
    const int g = l >> 4;       // edge group 0..3
    const int q = l & 15;       // feature quad 0..15

    const float dc = dinv[n];
    float ax = 0.f, ay = 0.f, az = 0.f, aw = 0.f;

    // self-loop in group 0
    if (g == 0) {
        float4 xv = *(const float4*)&h[n * DF + q * 4];
        ax = xv.x * dc; ay = xv.y * dc; az = xv.z * dc; aw = xv.w * dc;
    }

    const int s0 = offs[n], s1 = offs[n + 1];
    int s = s0;
    for (; s + 8 <= s1; s += 8) {
        int r0 = esrc[s + g];
        int r1 = esrc[s + 4 + g];
        float w0 = dinv[r0], w1 = dinv[r1];
        float4 v0 = *(const float4*)&h[r0 * DF + q * 4];
        float4 v1 = *(const float4*)&h[r1 * DF + q * 4];
        ax += v0.x * w0; ay += v0.y * w0; az += v0.z * w0; aw += v0.w * w0;
        ax += v1.x * w1; ay += v1.y * w1; az += v1.z * w1; aw += v1.w * w1;
    }
    for (; s < s1; s += 4) {
        int idx = s + g;
        bool valid = idx < s1;
        int r = valid ? esrc[idx] : n;
        float w = valid ? dinv[r] : 0.f;
        float4 v = *(const float4*)&h[r * DF + q * 4];
        ax += v.x * w; ay += v.y * w; az += v.z * w; aw += v.w * w;
    }

    // fold the 4 edge groups
    ax += __shfl_xor(ax, 16); ay += __shfl_xor(ay, 16);
    az += __shfl_xor(az, 16); aw += __shfl_xor(aw, 16);
    ax += __shfl_xor(ax, 32); ay += __shfl_xor(ay, 32);
    az += __shfl_xor(az, 32); aw += __shfl_xor(aw, 32);

    if (l < 16)
        *(float4*)&agg[n * DF + q * 4] =
            make_float4(ax * dc, ay * dc, az * dc, aw * dc);
}

// ---------------- hierarchical pool (batch is sorted); input already relu'd ----------------
#define POOL_NPW 128   // nodes per wave

__global__ __launch_bounds__(256)
void k_pool2(const float* __restrict__ h, const int* __restrict__ batch,
             float* __restrict__ pool, float* __restrict__ cnt) {
    const int wave = threadIdx.x >> 6;
    const int d    = threadIdx.x & 63;
    int n0 = (blockIdx.x * 4 + wave) * POOL_NPW;
    if (n0 >= N_NODES) return;
    int n1 = n0 + POOL_NPW; if (n1 > N_NODES) n1 = N_NODES;
    float acc = 0.f, c = 0.f;
    int g = batch[n0];
    for (int n = n0; n < n1; ++n) {
        int bg = batch[n];                 // wave-uniform broadcast
        if (bg != g) {
            atomicAdd(&pool[g * DF + d], acc);
            if (d == 0) atomicAdd(&cnt[g], c);
            acc = 0.f; c = 0.f; g = bg;
        }
        acc += h[n * DF + d];
        c += 1.f;
    }
    atomicAdd(&pool[g * DF + d], acc);
    if (d == 0) atomicAdd(&cnt[g], c);
}

__global__ void k_div(const float* __restrict__ pool, const float* __restrict__ cnt,
                      float* __restrict__ out) {
    int idx = blockIdx.x * blockDim.x + threadIdx.x;
    if (idx < N_GRAPHS * DF) {
        float c = cnt[idx >> 6];
        out[idx] = pool[idx] / fmaxf(c, 1.0f);
    }
}

// ---------------- launch ----------------

extern "C" void kernel_launch(void* const* d_in, const int* in_sizes, int n_in,
                              void* d_out, int out_size, void* d_ws, size_t ws_size,
                              hipStream_t stream) {
    const float* x     = (const float*)d_in[0];
    const int*   ei    = (const int*)d_in[1];      // [2, E] flat: row then col
    const int*   batch = (const int*)d_in[2];
    const float* W1    = (const float*)d_in[3];
    const float* b1    = (const float*)d_in[4];
    const float* W2    = (const float*)d_in[5];
    const float* b2    = (const float*)d_in[6];
    const float* W3    = (const float*)d_in[7];
    const float* b3    = (const float*)d_in[8];
    float* out = (float*)d_out;

    const int* row = ei;             // source
    const int* col = ei + N_EDGES;   // target (aggregation index)

    // workspace layout (4-byte elements)
    // [cnti NPAD][pool 4096][cnt 64]  <- zeroed in ONE memset
    char* wsb = (char*)d_ws;
    int*   cnti   = (int*)wsb;                       // NPAD
    float* pool   = (float*)(cnti + NPAD);           // N_GRAPHS*DF
    float* cnt    = pool + N_GRAPHS * DF;            // N_GRAPHS
    int*   offs   = (int*)(cnt + N_GRAPHS);          // NPAD
    int*   cursor = offs + NPAD;                     // NPAD
    int*   bsum   = cursor + NPAD;                   // 256
    int*   esrc   = bsum + 256;                      // N_EDGES
    float* dinv   = (float*)(esrc + N_EDGES);        // NPAD
    float* bufA   = dinv + NPAD;                     // N_NODES*DF
    float* bufB   = bufA + N_NODES * DF;             // N_NODES*DF

    const int nblk_E  = (N_EDGES + 255) / 256;       // 3125
    const int nblk_G  = (N_NODES + GB_ROWS - 1) / GB_ROWS;   // 782
    const int nblk_GA = (N_NODES + 3) / 4;           // 12500, 1 wave/node
    const int nblk_P  = (N_NODES + 4 * POOL_NPW - 1) / (4 * POOL_NPW); // 98

    // zero cnti + pool + cnt in one shot
    hipMemsetAsync(cnti, 0, (NPAD + N_GRAPHS * DF + N_GRAPHS) * sizeof(int), stream);

    // CSR build + dinv
    k_count<<<nblk_E, 256, 0, stream>>>(col, cnti);
    k_scan_block<<<196, 256, 0, stream>>>(cnti, offs, bsum, dinv);
    k_scan_bsum<<<1, 64, 0, stream>>>(bsum);
    k_scan_add<<<196, 256, 0, stream>>>(offs, bsum, cursor);
    k_fill<<<nblk_E, 256, 0, stream>>>(row, col, cursor, esrc);

    // layer 1: agg = A_hat x ; h1 = relu(agg @ W1 + b1)   [(A_hat X)W == A_hat(XW)]
    k_gather<<<nblk_GA, 256, 0, stream>>>(offs, esrc, dinv, x, bufA);
    k_gemm<<<nblk_G, 256, 0, stream>>>(bufA, W1, b1, bufB, 1);
    // layer 2
    k_gather<<<nblk_GA, 256, 0, stream>>>(offs, esrc, dinv, bufB, bufA);
    k_gemm<<<nblk_G, 256, 0, stream>>>(bufA, W2, b2, bufB, 1);
    // layer 3
    k_gather<<<nblk_GA, 256, 0, stream>>>(offs, esrc, dinv, bufB, bufA);
    k_gemm<<<nblk_G, 256, 0, stream>>>(bufA, W3, b3, bufB, 1);

    // mean pool
    k_pool2<<<nblk_P, 256, 0, stream>>>(bufB, batch, pool, cnt);
    k_div<<<(N_GRAPHS * DF + 255) / 256, 256, 0, stream>>>(pool, cnt, out);
}